// Round 6
// baseline (383.117 us; speedup 1.0000x reference)
//
#include <hip/hip_runtime.h>

// ---------------------------------------------------------------------------
// InterpNetwork: G=2, T=33, D=96, H=128, PROJ=128.
// feat@ud_W1 = P[t+1,i] + Q[t,j] + C[i,j]  (concat split) =>
// per-edge work = layer2 (128->64) + layer3 (64->1) via MFMA.
// Round 6: 2 launches.
//   kA (684 blocks): blocks 0..30 transpose weights -> per-block MAGIC flag;
//       all blocks spin on the 31 flags (all co-resident: 684 << capacity,
//       so no deadlock regardless of dispatch order); then units 0..395 =
//       node-enc L1+L2 + fused P/Q (enc kept in LDS), 396..683 = E2 codes.
//   kB (1280 blocks): edge MLP tiles + dist head (verified, unchanged).
// ---------------------------------------------------------------------------

typedef __bf16 bf16_t;
typedef bf16_t bf16x8 __attribute__((ext_vector_type(8)));
typedef float  f32x4  __attribute__((ext_vector_type(4)));

#define XS_LD 136
#define NEGV  -1000000000.0f
#define FLAG_MAGIC 0x5AC0FFEEu

// ---------------------------------------------------------------------------
// kA: fused weight-prep + node encoder + edge codes.
// ---------------------------------------------------------------------------
__global__ __launch_bounds__(256) void kA(
    const float* __restrict__ x,
    const float* __restrict__ neW1, const float* __restrict__ neW2,
    const float* __restrict__ udW1, const float* __restrict__ udW2,
    const float* __restrict__ dpW1, const float* __restrict__ dpW2,
    const float* __restrict__ eeW2,
    const float* __restrict__ neb1, const float* __restrict__ neb2,
    const float* __restrict__ edge_w,
    const float* __restrict__ eeW1, const float* __restrict__ eeb1,
    const float* __restrict__ eeb2,
    bf16_t* __restrict__ neW1T, bf16_t* __restrict__ neW2T,
    bf16_t* __restrict__ udW1aT, bf16_t* __restrict__ udW1bT,
    bf16_t* __restrict__ W1cT, bf16_t* __restrict__ udW2T,
    bf16_t* __restrict__ dpW1T, bf16_t* __restrict__ dpW2T,
    bf16_t* __restrict__ W2eT,
    bf16_t* __restrict__ encB, bf16_t* __restrict__ P, bf16_t* __restrict__ Q,
    bf16_t* __restrict__ E2g,
    unsigned int* __restrict__ flags) {
  __shared__ char smem[64 * 65 * 4];             // 16.6 KB, unioned
  int bid = blockIdx.x, tid = threadIdx.x;
  int l = tid & 63, w = tid >> 6, lr = l & 15, lg = l >> 4;

  // ===== phase 0: weight transposes (blocks 0..30), then flag =====
  if (bid < 31) {
    static const unsigned char tSrc[31] = {0,0,0,0, 1,1,1,1, 2,2,2,2, 2,2,2,2, 2,2, 3,3, 4,4,4,4,4,4,4,4, 5,5, 6};
    static const unsigned char tDst[31] = {0,0,0,0, 1,1,1,1, 2,2,2,2, 3,3,3,3, 4,4, 5,5, 6,6,6,6,6,6,6,6, 7,7, 8};
    static const short tLdS[31] = {128,128,128,128, 128,128,128,128, 128,128,128,128, 128,128,128,128, 128,128, 64,64, 128,128,128,128,128,128,128,128, 64,64, 32};
    static const short tLdD[31] = {128,128,128,128, 128,128,128,128, 128,128,128,128, 128,128,128,128, 32,32, 128,128, 256,256,256,256,256,256,256,256, 128,128, 32};
    static const short tR0[31]  = {0,0,64,64, 0,0,64,64, 0,0,64,64, 128,128,192,192, 256,256, 0,64, 0,0,64,64,128,128,192,192, 0,64, 0};
    static const short tC0[31]  = {0,64,0,64, 0,64,0,64, 0,64,0,64, 0,64,0,64, 0,64, 0,0, 0,64,0,64,0,64,0,64, 0,0, 0};
    static const short tRB[31]  = {0,0,0,0, 0,0,0,0, 0,0,0,0, 128,128,128,128, 256,256, 0,0, 0,0,0,0,0,0,0,0, 0,0, 0};
    static const unsigned char tNR[31] = {64,64,64,64, 64,64,64,64, 64,64,64,64, 64,64,64,64, 32,32, 64,64, 64,64,64,64,64,64,64,64, 64,64, 32};
    static const unsigned char tNC[31] = {64,64,64,64, 64,64,64,64, 64,64,64,64, 64,64,64,64, 64,64, 64,64, 64,64,64,64,64,64,64,64, 64,64, 32};
    const float* S;
    switch (tSrc[bid]) {
      case 0: S = neW1; break; case 1: S = neW2; break; case 2: S = udW1; break;
      case 3: S = udW2; break; case 4: S = dpW1; break; case 5: S = dpW2; break;
      default: S = eeW2; break;
    }
    bf16_t* Dst;
    switch (tDst[bid]) {
      case 0: Dst = neW1T; break; case 1: Dst = neW2T; break; case 2: Dst = udW1aT; break;
      case 3: Dst = udW1bT; break; case 4: Dst = W1cT; break; case 5: Dst = udW2T; break;
      case 6: Dst = dpW1T; break; case 7: Dst = dpW2T; break; default: Dst = W2eT; break;
    }
    int ldS = tLdS[bid], ldD = tLdD[bid], r0 = tR0[bid], c0 = tC0[bid], rb = tRB[bid];
    int nR = tNR[bid], nC = tNC[bid];
    float (*tile)[65] = (float(*)[65])smem;
    #pragma unroll
    for (int i = 0; i < 16; ++i) {
      int idx = tid + i * 256, r = idx >> 6, c = idx & 63;
      if (r < nR && c < nC) tile[r][c] = S[(r0 + r) * ldS + c0 + c];
    }
    __syncthreads();
    #pragma unroll
    for (int i = 0; i < 16; ++i) {
      int idx = tid + i * 256, n = idx >> 6, k = idx & 63;
      if (n < nC && k < nR) Dst[(c0 + n) * ldD + (r0 - rb) + k] = (bf16_t)tile[k][n];
    }
    __threadfence();
    __syncthreads();
    if (tid == 0)
      __hip_atomic_store(&flags[bid], FLAG_MAGIC, __ATOMIC_RELEASE, __HIP_MEMORY_SCOPE_AGENT);
  }

  // ===== all blocks: wait for the 31 transpose flags =====
  if (tid == 0) {
    for (;;) {
      int ok = 1;
      #pragma unroll 1
      for (int i = 0; i < 31; ++i) {
        if (__hip_atomic_load(&flags[i], __ATOMIC_ACQUIRE, __HIP_MEMORY_SCOPE_AGENT) != FLAG_MAGIC) { ok = 0; break; }
      }
      if (ok) break;
      __builtin_amdgcn_s_sleep(8);
    }
  }
  __syncthreads();

  // ===== phase 1 =====
  if (bid < 396) {
    // node-enc unit (g,s,mt): 16 rows; L1+L2 in LDS, fused P/Q.
    bf16_t* sX = (bf16_t*)smem;                    // 16 x 136
    bf16_t* sH = (bf16_t*)smem + 16 * 136;
    bf16_t* sE = (bf16_t*)smem + 32 * 136;
    int ub = bid / 6, mt = bid % 6, g = ub / 33;
    const float* xsrc = x + (size_t)ub * 128 * 192 + g * 96 + mt * 16;  // [h*192+dl]
    #pragma unroll
    for (int i = 0; i < 2; ++i) {
      int t = tid + i * 256;                 // 0..511
      int h = t >> 2, c4 = (t & 3) * 4;
      f32x4 v = *(const f32x4*)(xsrc + h * 192 + c4);
      #pragma unroll
      for (int r = 0; r < 4; ++r) sX[(c4 + r) * 136 + h] = (bf16_t)v[r];
    }
    __syncthreads();

    // layer1: sX -> sH
    {
      bf16x8 a[4];
      #pragma unroll
      for (int ks = 0; ks < 4; ++ks)
        a[ks] = *(const bf16x8*)(sX + lr * 136 + ks * 32 + lg * 8);
      #pragma unroll
      for (int nn = 0; nn < 2; ++nn) {
        int nb = w * 2 + nn;
        f32x4 acc = {0.f,0.f,0.f,0.f};
        #pragma unroll
        for (int ks = 0; ks < 4; ++ks) {
          bf16x8 bfr = *(const bf16x8*)(neW1T + (nb*16 + lr)*128 + ks*32 + lg*8);
          acc = __builtin_amdgcn_mfma_f32_16x16x32_bf16(a[ks], bfr, acc, 0, 0, 0);
        }
        float bv = neb1[nb*16 + lr];
        #pragma unroll
        for (int r = 0; r < 4; ++r)
          sH[(lg*4 + r)*136 + nb*16 + lr] = (bf16_t)fmaxf(acc[r] + bv, 0.f);
      }
    }
    __syncthreads();

    // layer2: sH -> sE + encB
    bf16_t* encOut = encB + ((size_t)ub * 96 + mt * 16) * 128;
    {
      bf16x8 a[4];
      #pragma unroll
      for (int ks = 0; ks < 4; ++ks)
        a[ks] = *(const bf16x8*)(sH + lr * 136 + ks * 32 + lg * 8);
      #pragma unroll
      for (int nn = 0; nn < 2; ++nn) {
        int nb = w * 2 + nn;
        f32x4 acc = {0.f,0.f,0.f,0.f};
        #pragma unroll
        for (int ks = 0; ks < 4; ++ks) {
          bf16x8 bfr = *(const bf16x8*)(neW2T + (nb*16 + lr)*128 + ks*32 + lg*8);
          acc = __builtin_amdgcn_mfma_f32_16x16x32_bf16(a[ks], bfr, acc, 0, 0, 0);
        }
        float bv = neb2[nb*16 + lr];
        #pragma unroll
        for (int r = 0; r < 4; ++r) {
          bf16_t v = (bf16_t)fmaxf(acc[r] + bv, 0.f);
          sE[(lg*4 + r)*136 + nb*16 + lr] = v;
          encOut[(lg*4 + r)*128 + nb*16 + lr] = v;
        }
      }
    }
    __syncthreads();

    // P/Q projection from sE (wave0/1 -> P cols 0-63/64-127, wave2/3 -> Q)
    {
      bf16x8 a[4];
      #pragma unroll
      for (int ks = 0; ks < 4; ++ks)
        a[ks] = *(const bf16x8*)(sE + lr * 136 + ks * 32 + lg * 8);
      const bf16_t* BW = (w < 2) ? udW1aT : udW1bT;
      bf16_t* outp = (w < 2) ? P : Q;
      int noff = (w & 1) * 64;
      #pragma unroll
      for (int nb = 0; nb < 4; ++nb) {
        f32x4 acc = {0.f,0.f,0.f,0.f};
        #pragma unroll
        for (int ks = 0; ks < 4; ++ks) {
          bf16x8 bfr = *(const bf16x8*)(BW + (noff + nb*16 + lr)*128 + ks*32 + lg*8);
          acc = __builtin_amdgcn_mfma_f32_16x16x32_bf16(a[ks], bfr, acc, 0, 0, 0);
        }
        #pragma unroll
        for (int r = 0; r < 4; ++r)
          outp[((size_t)ub*96 + mt*16 + lg*4 + r)*128 + noff + nb*16 + lr] = (bf16_t)acc[r];
      }
    }
  } else {
    // E2 edge codes: 64 edges per block, 16 per wave
    int u3 = bid - 396;
    int e0 = u3 * 64 + w * 16;
    int e = e0 + lr;
    int g = e / 9216, rem = e - g * 9216, i = rem / 96, j = rem - i * 96;
    float wv = edge_w[(g*96 + i)*192 + g*96 + j];
    bf16x8 ah;
    #pragma unroll
    for (int m = 0; m < 8; ++m) {
      int k = lg * 8 + m;
      ah[m] = (bf16_t)fmaxf(wv * eeW1[k] + eeb1[k], 0.f);
    }
    #pragma unroll
    for (int nb = 0; nb < 2; ++nb) {
      bf16x8 bw = *(const bf16x8*)(W2eT + (nb*16 + lr)*32 + lg*8);
      f32x4 acc = {0.f,0.f,0.f,0.f};
      acc = __builtin_amdgcn_mfma_f32_16x16x32_bf16(ah, bw, acc, 0, 0, 0);
      float b2 = eeb2[nb*16 + lr];
      #pragma unroll
      for (int r = 0; r < 4; ++r)
        E2g[((size_t)e0 + lg*4 + r)*32 + nb*16 + lr] = (bf16_t)fmaxf(acc[r] + b2, 0.f);
    }
  }
}

// ---------------------------------------------------------------------------
// kB: blocks 0..1151 = edge MLP tiles (jt,it,z); 1152..1279 = dist head.
// (verified in rounds 4/5, unchanged)
// ---------------------------------------------------------------------------
__global__ __launch_bounds__(256) void kB(
    const bf16_t* __restrict__ P, const bf16_t* __restrict__ Q,
    const bf16_t* __restrict__ E2g, const bf16_t* __restrict__ W1cT,
    const bf16_t* __restrict__ udW2T,
    const float* __restrict__ udb1, const float* __restrict__ udb2,
    const float* __restrict__ udW3, const float* __restrict__ udb3,
    const float* __restrict__ edge_w, float* __restrict__ out_logits,
    const bf16_t* __restrict__ encB,
    const bf16_t* __restrict__ dpW1T, const float* __restrict__ dpb1,
    const bf16_t* __restrict__ dpW2T, const float* __restrict__ dpb2,
    const float* __restrict__ dpW3, const float* __restrict__ dpb3,
    float* __restrict__ dist_out) {
  __shared__ bf16_t smem[2 * 64 * XS_LD];          // 34.8 KB
  bf16_t* sb0 = smem;
  bf16_t* sb1 = smem + 64 * XS_LD;
  int b = blockIdx.x, tid = threadIdx.x;
  int l = tid & 63, w = tid >> 6, lr = l & 15, lg = l >> 4;

  if (b < 1152) {
    int jt = b % 12, it = (b / 12) % 12, z = b / 144;
    int g = z >> 2, tc = z & 3;
    int i0 = it * 8, j0 = jt * 8;
    int e_loc = w * 16 + lr, ii = e_loc >> 3, jj = e_loc & 7;

    bf16x8 pst[4], qst[4];
    #pragma unroll
    for (int r = 0; r < 4; ++r) {
      int c = tid + r * 256;
      int row = c >> 4, kc = c & 15;
      int tt = row >> 3, rr = row & 7;
      pst[r] = *(const bf16x8*)(P + ((size_t)((g*33 + tc*8 + tt + 1)*96) + i0 + rr)*128 + kc*8);
      qst[r] = *(const bf16x8*)(Q + ((size_t)((g*33 + tc*8 + tt)*96) + j0 + rr)*128 + kc*8);
    }

    bf16x8 wb[4][4];
    #pragma unroll
    for (int nb = 0; nb < 4; ++nb)
      #pragma unroll
      for (int ks = 0; ks < 4; ++ks)
        wb[nb][ks] = *(const bf16x8*)(udW2T + (nb*16 + lr)*128 + ks*32 + lg*8);
    float b2v[4], w3v[4], b1v[8];
    #pragma unroll
    for (int nb = 0; nb < 4; ++nb) { b2v[nb] = udb2[nb*16 + lr]; w3v[nb] = udW3[nb*16 + lr]; }
    #pragma unroll
    for (int nb = 0; nb < 8; ++nb) b1v[nb] = udb1[nb*16 + lr];
    float b3 = udb3[0];

    int orow = w*16 + lg*4 + (lr & 3);
    int mi = i0 + (orow >> 3), mj = j0 + (orow & 7);
    float ewv = edge_w[(g*96 + mi)*192 + g*96 + mj];
    bool dead = (ewv == 0.0f) && (mi != mj);

    {
      bf16x8 ae = *(const bf16x8*)(E2g + ((size_t)((g*96 + i0 + ii)*96) + j0 + jj)*32 + lg*8);
      #pragma unroll
      for (int nb = 0; nb < 8; ++nb) {
        bf16x8 bw = *(const bf16x8*)(W1cT + (nb*16 + lr)*32 + lg*8);
        f32x4 acc = {0.f,0.f,0.f,0.f};
        acc = __builtin_amdgcn_mfma_f32_16x16x32_bf16(ae, bw, acc, 0, 0, 0);
        #pragma unroll
        for (int r = 0; r < 4; ++r)
          sb0[(w*16 + lg*4 + r)*XS_LD + nb*16 + lr] = (bf16_t)(acc[r] + b1v[nb]);
      }
    }
    __syncthreads();
    float csf[32];
    #pragma unroll
    for (int ks = 0; ks < 4; ++ks) {
      bf16x8 cv = *(const bf16x8*)(sb0 + e_loc*XS_LD + ks*32 + lg*8);
      #pragma unroll
      for (int m = 0; m < 8; ++m) csf[ks*8 + m] = (float)cv[m];
    }
    __syncthreads();
    #pragma unroll
    for (int r = 0; r < 4; ++r) {
      int c = tid + r * 256;
      int row = c >> 4, kc = c & 15;
      *(bf16x8*)(sb0 + row*XS_LD + kc*8) = pst[r];
      *(bf16x8*)(sb1 + row*XS_LD + kc*8) = qst[r];
    }
    __syncthreads();

    #pragma unroll 2
    for (int tt = 0; tt < 8; ++tt) {
      int prow = tt*8 + ii, qrow = tt*8 + jj;
      bf16x8 a[4];
      #pragma unroll
      for (int ks = 0; ks < 4; ++ks) {
        bf16x8 pv = *(const bf16x8*)(sb0 + prow*XS_LD + ks*32 + lg*8);
        bf16x8 qv = *(const bf16x8*)(sb1 + qrow*XS_LD + ks*32 + lg*8);
        #pragma unroll
        for (int m = 0; m < 8; ++m) {
          float s = (float)pv[m] + (float)qv[m] + csf[ks*8 + m];
          a[ks][m] = (bf16_t)fmaxf(s, 0.f);
        }
      }
      f32x4 acc[4];
      #pragma unroll
      for (int nb = 0; nb < 4; ++nb) {
        f32x4 t4 = {0.f,0.f,0.f,0.f};
        #pragma unroll
        for (int ks = 0; ks < 4; ++ks)
          t4 = __builtin_amdgcn_mfma_f32_16x16x32_bf16(a[ks], wb[nb][ks], t4, 0, 0, 0);
        acc[nb] = t4;
      }
      float partial[4];
      #pragma unroll
      for (int r = 0; r < 4; ++r) {
        float ps = 0.f;
        #pragma unroll
        for (int nb = 0; nb < 4; ++nb)
          ps += fmaxf(acc[nb][r] + b2v[nb], 0.f) * w3v[nb];
        partial[r] = ps;
      }
      #pragma unroll
      for (int r = 0; r < 4; ++r) {
        partial[r] += __shfl_xor(partial[r], 1, 16);
        partial[r] += __shfl_xor(partial[r], 2, 16);
        partial[r] += __shfl_xor(partial[r], 4, 16);
        partial[r] += __shfl_xor(partial[r], 8, 16);
      }
      if (lr < 4) {
        float v = (lr == 0) ? partial[0] : (lr == 1) ? partial[1]
                : (lr == 2) ? partial[2] : partial[3];
        v = dead ? NEGV : (v + b3);
        out_logits[(size_t)((g*32 + tc*8 + tt)*96 + mi)*96 + mj] = v;
      }
    }
  } else {
    int u = b - 1152;
    int g = u >> 6, t = (u >> 1) & 31, half = u & 1;
    int r0 = half * 48;
    if (w < 3) {
      bf16x8 a[8];
      #pragma unroll
      for (int ks = 0; ks < 8; ++ks) {
        int h2 = ks >> 2;
        int kk = (ks & 3)*32 + lg*8;
        a[ks] = *(const bf16x8*)(encB + (size_t)((g*33 + t + h2)*96 + r0 + w*16 + lr)*128 + kk);
      }
      #pragma unroll
      for (int nb = 0; nb < 8; ++nb) {
        f32x4 acc = {0.f,0.f,0.f,0.f};
        #pragma unroll
        for (int ks = 0; ks < 8; ++ks) {
          bf16x8 bfr = *(const bf16x8*)(dpW1T + (size_t)(nb*16 + lr)*256 + ks*32 + lg*8);
          acc = __builtin_amdgcn_mfma_f32_16x16x32_bf16(a[ks], bfr, acc, 0, 0, 0);
        }
        int n = nb*16 + lr; float bv = dpb1[n];
        #pragma unroll
        for (int r = 0; r < 4; ++r)
          sb0[(w*16 + lg*4 + r)*XS_LD + n] = (bf16_t)fmaxf(acc[r] + bv, 0.f);
      }
    }
    __syncthreads();
    if (w < 3) {
      bf16x8 a2[4];
      #pragma unroll
      for (int ks = 0; ks < 4; ++ks)
        a2[ks] = *(const bf16x8*)(sb0 + (w*16 + lr)*XS_LD + ks*32 + lg*8);
      f32x4 acc[4];
      #pragma unroll
      for (int nb = 0; nb < 4; ++nb) {
        f32x4 t4 = {0.f,0.f,0.f,0.f};
        #pragma unroll
        for (int ks = 0; ks < 4; ++ks) {
          bf16x8 bfr = *(const bf16x8*)(dpW2T + (nb*16 + lr)*128 + ks*32 + lg*8);
          t4 = __builtin_amdgcn_mfma_f32_16x16x32_bf16(a2[ks], bfr, t4, 0, 0, 0);
        }
        acc[nb] = t4;
      }
      float b2v[4], w3v[4];
      #pragma unroll
      for (int nb = 0; nb < 4; ++nb) { b2v[nb] = dpb2[nb*16 + lr]; w3v[nb] = dpW3[nb*16 + lr]; }
      float partial[4];
      #pragma unroll
      for (int r = 0; r < 4; ++r) {
        float ps = 0.f;
        #pragma unroll
        for (int nb = 0; nb < 4; ++nb)
          ps += fmaxf(acc[nb][r] + b2v[nb], 0.f) * w3v[nb];
        partial[r] = ps;
      }
      #pragma unroll
      for (int r = 0; r < 4; ++r) {
        partial[r] += __shfl_xor(partial[r], 1, 16);
        partial[r] += __shfl_xor(partial[r], 2, 16);
        partial[r] += __shfl_xor(partial[r], 4, 16);
        partial[r] += __shfl_xor(partial[r], 8, 16);
      }
      if (lr < 4) {
        float v = (lr == 0) ? partial[0] : (lr == 1) ? partial[1]
                : (lr == 2) ? partial[2] : partial[3];
        v += dpb3[0];
        int row = r0 + w*16 + lg*4 + lr;
        dist_out[(size_t)(g*32 + t)*96 + row] = v;
      }
    }
  }
}

// ---------------------------------------------------------------------------
extern "C" void kernel_launch(void* const* d_in, const int* in_sizes, int n_in,
                              void* d_out, int out_size, void* d_ws, size_t ws_size,
                              hipStream_t stream) {
  (void)in_sizes; (void)n_in; (void)out_size; (void)ws_size;
  const float* x      = (const float*)d_in[0];
  const float* edge_w = (const float*)d_in[1];
  const float* neW1 = (const float*)d_in[5];
  const float* neb1 = (const float*)d_in[6];
  const float* neW2 = (const float*)d_in[7];
  const float* neb2 = (const float*)d_in[8];
  const float* eeW1 = (const float*)d_in[9];
  const float* eeb1 = (const float*)d_in[10];
  const float* eeW2 = (const float*)d_in[11];
  const float* eeb2 = (const float*)d_in[12];
  const float* udW1 = (const float*)d_in[13];
  const float* udb1 = (const float*)d_in[14];
  const float* udW2 = (const float*)d_in[15];
  const float* udb2 = (const float*)d_in[16];
  const float* udW3 = (const float*)d_in[17];
  const float* udb3 = (const float*)d_in[18];
  const float* dpW1 = (const float*)d_in[19];
  const float* dpb1 = (const float*)d_in[20];
  const float* dpW2 = (const float*)d_in[21];
  const float* dpb2 = (const float*)d_in[22];
  const float* dpW3 = (const float*)d_in[23];
  const float* dpb3 = (const float*)d_in[24];

  char* ws = (char*)d_ws;
  size_t off = 0;
  auto alloc = [&](size_t bytes) -> char* {
    off = (off + 255) & ~(size_t)255;
    char* p = ws + off;
    off += bytes;
    return p;
  };
  bf16_t* encB   = (bf16_t*)alloc((size_t)2*33*96*128 * 2);
  bf16_t* Pbuf   = (bf16_t*)alloc((size_t)2*33*96*128 * 2);
  bf16_t* Qbuf   = (bf16_t*)alloc((size_t)2*33*96*128 * 2);
  bf16_t* E2g    = (bf16_t*)alloc((size_t)2*96*96*32  * 2);
  bf16_t* neW1T  = (bf16_t*)alloc(16384 * 2);
  bf16_t* neW2T  = (bf16_t*)alloc(16384 * 2);
  bf16_t* udW1aT = (bf16_t*)alloc(16384 * 2);
  bf16_t* udW1bT = (bf16_t*)alloc(16384 * 2);
  bf16_t* W1cT   = (bf16_t*)alloc(4096  * 2);
  bf16_t* udW2T  = (bf16_t*)alloc(8192  * 2);
  bf16_t* dpW1T  = (bf16_t*)alloc(32768 * 2);
  bf16_t* dpW2T  = (bf16_t*)alloc(8192  * 2);
  bf16_t* W2eT   = (bf16_t*)alloc(1024  * 2);
  unsigned int* flags = (unsigned int*)alloc(31 * 4);

  float* out_logits = (float*)d_out;                 // (2,32,96,96)
  float* dist_out   = (float*)d_out + 2*32*96*96;    // (2,32,96)

  kA<<<dim3(684), dim3(256), 0, stream>>>(
      x, neW1, neW2, udW1, udW2, dpW1, dpW2, eeW2,
      neb1, neb2, edge_w, eeW1, eeb1, eeb2,
      neW1T, neW2T, udW1aT, udW1bT, W1cT, udW2T, dpW1T, dpW2T, W2eT,
      encB, Pbuf, Qbuf, E2g, flags);

  kB<<<dim3(1280), dim3(256), 0, stream>>>(
      Pbuf, Qbuf, E2g, W1cT, udW2T, udb1, udb2, udW3, udb3, edge_w, out_logits,
      encB, dpW1T, dpb1, dpW2T, dpb2, dpW3, dpb3, dist_out);
}

// Round 7
// 155.618 us; speedup vs baseline: 2.4619x; 2.4619x over previous
//
#include <hip/hip_runtime.h>

// ---------------------------------------------------------------------------
// InterpNetwork: G=2, T=33, D=96, H=128, PROJ=128.
// feat@ud_W1 = P[t+1,i] + Q[t,j] + C[i,j]  (concat split) =>
// per-edge work = layer2 (128->64) + layer3 (64->1) via MFMA.
// Round 7: 2 launches, NO weight-prep pass. Each wave gathers its MFMA
// B-fragments directly from the original f32 [K][N] weights (stride-N
// scalar loads, 16 contiguous lanes/row -> 4 cache lines per instr,
// all L2-resident). grid.sync (r4: ~60us/sync) and device-scope flag
// spins (r6: ~240us) are both worse than a launch boundary (~15us).
//   kEnc (684 blocks): 0..395 node-enc L1+L2 + fused P/Q; 396..683 E2 codes.
//   kB   (704 blocks): 0..575 edge-MLP tiles (16 t each); 576..703 dist head.
// ---------------------------------------------------------------------------

typedef __bf16 bf16_t;
typedef bf16_t bf16x8 __attribute__((ext_vector_type(8)));
typedef float  f32x4  __attribute__((ext_vector_type(4)));

#define XS_LD 136
#define NEGV  -1000000000.0f

// gather one B-fragment (8 k-elems at fixed n) from f32 [K][N] weight
__device__ __forceinline__ bf16x8 gfrag(const float* p, int ld) {
  bf16x8 r;
  #pragma unroll
  for (int m = 0; m < 8; ++m) r[m] = (bf16_t)p[m * ld];
  return r;
}

// ---------------------------------------------------------------------------
// kEnc: units 0..395 = (g,s,mt) 16-row node-enc L1+L2 + fused P/Q;
//       units 396..683 = 64-edge E2 codes. 256 threads, 4 waves.
// ---------------------------------------------------------------------------
__global__ __launch_bounds__(256) void kEnc(
    const float* __restrict__ x,
    const float* __restrict__ neW1, const float* __restrict__ neb1,
    const float* __restrict__ neW2, const float* __restrict__ neb2,
    const float* __restrict__ udW1,
    bf16_t* __restrict__ encB, bf16_t* __restrict__ P, bf16_t* __restrict__ Q,
    const float* __restrict__ edge_w,
    const float* __restrict__ eeW1, const float* __restrict__ eeb1,
    const float* __restrict__ eeW2, const float* __restrict__ eeb2,
    bf16_t* __restrict__ E2g) {
  __shared__ bf16_t sX[16 * 136];
  __shared__ bf16_t sH[16 * 136];
  __shared__ bf16_t sE[16 * 136];
  int bid = blockIdx.x, tid = threadIdx.x;
  int l = tid & 63, w = tid >> 6, lr = l & 15, lg = l >> 4;

  if (bid < 396) {
    int ub = bid / 6, mt = bid % 6, g = ub / 33;
    const float* xsrc = x + (size_t)ub * 128 * 192 + g * 96 + mt * 16;  // [h*192+dl]
    #pragma unroll
    for (int i = 0; i < 2; ++i) {
      int t = tid + i * 256;                 // 0..511
      int h = t >> 2, c4 = (t & 3) * 4;
      f32x4 v = *(const f32x4*)(xsrc + h * 192 + c4);
      #pragma unroll
      for (int r = 0; r < 4; ++r) sX[(c4 + r) * 136 + h] = (bf16_t)v[r];
    }
    __syncthreads();

    // layer1: sX -> sH   (B-frags gathered from f32 neW1 [128][128])
    {
      bf16x8 a[4];
      #pragma unroll
      for (int ks = 0; ks < 4; ++ks)
        a[ks] = *(const bf16x8*)(sX + lr * 136 + ks * 32 + lg * 8);
      #pragma unroll
      for (int nn = 0; nn < 2; ++nn) {
        int nb = w * 2 + nn;
        bf16x8 bw[4];
        #pragma unroll
        for (int ks = 0; ks < 4; ++ks)
          bw[ks] = gfrag(neW1 + (size_t)(ks*32 + lg*8)*128 + nb*16 + lr, 128);
        f32x4 acc = {0.f,0.f,0.f,0.f};
        #pragma unroll
        for (int ks = 0; ks < 4; ++ks)
          acc = __builtin_amdgcn_mfma_f32_16x16x32_bf16(a[ks], bw[ks], acc, 0, 0, 0);
        float bv = neb1[nb*16 + lr];
        #pragma unroll
        for (int r = 0; r < 4; ++r)
          sH[(lg*4 + r)*136 + nb*16 + lr] = (bf16_t)fmaxf(acc[r] + bv, 0.f);
      }
    }
    __syncthreads();

    // layer2: sH -> sE + encB
    bf16_t* encOut = encB + ((size_t)ub * 96 + mt * 16) * 128;
    {
      bf16x8 a[4];
      #pragma unroll
      for (int ks = 0; ks < 4; ++ks)
        a[ks] = *(const bf16x8*)(sH + lr * 136 + ks * 32 + lg * 8);
      #pragma unroll
      for (int nn = 0; nn < 2; ++nn) {
        int nb = w * 2 + nn;
        bf16x8 bw[4];
        #pragma unroll
        for (int ks = 0; ks < 4; ++ks)
          bw[ks] = gfrag(neW2 + (size_t)(ks*32 + lg*8)*128 + nb*16 + lr, 128);
        f32x4 acc = {0.f,0.f,0.f,0.f};
        #pragma unroll
        for (int ks = 0; ks < 4; ++ks)
          acc = __builtin_amdgcn_mfma_f32_16x16x32_bf16(a[ks], bw[ks], acc, 0, 0, 0);
        float bv = neb2[nb*16 + lr];
        #pragma unroll
        for (int r = 0; r < 4; ++r) {
          bf16_t v = (bf16_t)fmaxf(acc[r] + bv, 0.f);
          sE[(lg*4 + r)*136 + nb*16 + lr] = v;
          encOut[(lg*4 + r)*128 + nb*16 + lr] = v;
        }
      }
    }
    __syncthreads();

    // P/Q projection from sE; udW1 rows 0..127 -> P-cols, 128..255 -> Q-cols.
    {
      bf16x8 a[4];
      #pragma unroll
      for (int ks = 0; ks < 4; ++ks)
        a[ks] = *(const bf16x8*)(sE + lr * 136 + ks * 32 + lg * 8);
      int koff = (w < 2) ? 0 : 128;
      bf16_t* outp = (w < 2) ? P : Q;
      int noff = (w & 1) * 64;
      #pragma unroll
      for (int nb = 0; nb < 4; ++nb) {
        bf16x8 bw[4];
        #pragma unroll
        for (int ks = 0; ks < 4; ++ks)
          bw[ks] = gfrag(udW1 + (size_t)(koff + ks*32 + lg*8)*128 + noff + nb*16 + lr, 128);
        f32x4 acc = {0.f,0.f,0.f,0.f};
        #pragma unroll
        for (int ks = 0; ks < 4; ++ks)
          acc = __builtin_amdgcn_mfma_f32_16x16x32_bf16(a[ks], bw[ks], acc, 0, 0, 0);
        #pragma unroll
        for (int r = 0; r < 4; ++r)
          outp[((size_t)ub*96 + mt*16 + lg*4 + r)*128 + noff + nb*16 + lr] = (bf16_t)acc[r];
      }
    }
  } else {
    // E2 edge codes: 64 edges per block, 16 per wave; W2e f32 [32][32].
    int u3 = bid - 396;
    int e0 = u3 * 64 + w * 16;
    int e = e0 + lr;
    int g = e / 9216, rem = e - g * 9216, i = rem / 96, j = rem - i * 96;
    float wv = edge_w[(g*96 + i)*192 + g*96 + j];
    bf16x8 ah;
    #pragma unroll
    for (int m = 0; m < 8; ++m) {
      int k = lg * 8 + m;
      ah[m] = (bf16_t)fmaxf(wv * eeW1[k] + eeb1[k], 0.f);
    }
    #pragma unroll
    for (int nb = 0; nb < 2; ++nb) {
      bf16x8 bw = gfrag(eeW2 + (size_t)(lg*8)*32 + nb*16 + lr, 32);
      f32x4 acc = {0.f,0.f,0.f,0.f};
      acc = __builtin_amdgcn_mfma_f32_16x16x32_bf16(ah, bw, acc, 0, 0, 0);
      float b2 = eeb2[nb*16 + lr];
      #pragma unroll
      for (int r = 0; r < 4; ++r)
        E2g[((size_t)e0 + lg*4 + r)*32 + nb*16 + lr] = (bf16_t)fmaxf(acc[r] + b2, 0.f);
    }
  }
}

// ---------------------------------------------------------------------------
// kB: blocks 0..575 = edge MLP tiles (jt,it,g,t-half: 16 t each);
//     576..703 = dist head. All weights gathered from original f32.
// ---------------------------------------------------------------------------
__global__ __launch_bounds__(256) void kB(
    const bf16_t* __restrict__ P, const bf16_t* __restrict__ Q,
    const bf16_t* __restrict__ E2g,
    const float* __restrict__ udW1, const float* __restrict__ udW2,
    const float* __restrict__ udb1, const float* __restrict__ udb2,
    const float* __restrict__ udW3, const float* __restrict__ udb3,
    const float* __restrict__ edge_w, float* __restrict__ out_logits,
    const bf16_t* __restrict__ encB,
    const float* __restrict__ dpW1, const float* __restrict__ dpb1,
    const float* __restrict__ dpW2, const float* __restrict__ dpb2,
    const float* __restrict__ dpW3, const float* __restrict__ dpb3,
    float* __restrict__ dist_out) {
  __shared__ bf16_t smem[2 * 64 * XS_LD];          // 34.8 KB
  bf16_t* sb0 = smem;
  bf16_t* sb1 = smem + 64 * XS_LD;
  int b = blockIdx.x, tid = threadIdx.x;
  int l = tid & 63, w = tid >> 6, lr = l & 15, lg = l >> 4;

  if (b < 576) {
    int jt = b % 12, it = (b / 12) % 12, zz = b / 144;   // zz 0..3
    int g = zz >> 1, th = zz & 1;
    int i0 = it * 8, j0 = jt * 8;
    int e_loc = w * 16 + lr, ii = e_loc >> 3, jj = e_loc & 7;

    // layer-2 weights from udW2 f32 [128][64]
    bf16x8 wb[4][4];
    #pragma unroll
    for (int nb = 0; nb < 4; ++nb)
      #pragma unroll
      for (int ks = 0; ks < 4; ++ks)
        wb[nb][ks] = gfrag(udW2 + (size_t)(ks*32 + lg*8)*64 + nb*16 + lr, 64);
    float b2v[4], w3v[4], b1v[8];
    #pragma unroll
    for (int nb = 0; nb < 4; ++nb) { b2v[nb] = udb2[nb*16 + lr]; w3v[nb] = udW3[nb*16 + lr]; }
    #pragma unroll
    for (int nb = 0; nb < 8; ++nb) b1v[nb] = udb1[nb*16 + lr];
    float b3 = udb3[0];

    // mask (hoisted; valid for lanes lr<4 at store)
    int orow = w*16 + lg*4 + (lr & 3);
    int mi = i0 + (orow >> 3), mj = j0 + (orow & 7);
    float ewv = edge_w[(g*96 + mi)*192 + g*96 + mj];
    bool dead = (ewv == 0.0f) && (mi != mj);

    // C tile: sb0 = E2 @ W1c + b1 ; W1c = udW1 rows 256..287 (f32 [32][128])
    {
      bf16x8 ae = *(const bf16x8*)(E2g + ((size_t)((g*96 + i0 + ii)*96) + j0 + jj)*32 + lg*8);
      #pragma unroll
      for (int nb = 0; nb < 8; ++nb) {
        bf16x8 bw = gfrag(udW1 + (size_t)(256 + lg*8)*128 + nb*16 + lr, 128);
        f32x4 acc = {0.f,0.f,0.f,0.f};
        acc = __builtin_amdgcn_mfma_f32_16x16x32_bf16(ae, bw, acc, 0, 0, 0);
        #pragma unroll
        for (int r = 0; r < 4; ++r)
          sb0[(w*16 + lg*4 + r)*XS_LD + nb*16 + lr] = (bf16_t)(acc[r] + b1v[nb]);
      }
    }
    __syncthreads();
    float csf[32];
    #pragma unroll
    for (int ks = 0; ks < 4; ++ks) {
      bf16x8 cv = *(const bf16x8*)(sb0 + e_loc*XS_LD + ks*32 + lg*8);
      #pragma unroll
      for (int m = 0; m < 8; ++m) csf[ks*8 + m] = (float)cv[m];
    }

    // two t-chunks of 8 per block
    #pragma unroll 1
    for (int ph = 0; ph < 2; ++ph) {
      int tc = th*2 + ph;
      bf16x8 pst[4], qst[4];
      #pragma unroll
      for (int r = 0; r < 4; ++r) {
        int c = tid + r * 256;
        int row = c >> 4, kc = c & 15;
        int tt = row >> 3, rr = row & 7;
        pst[r] = *(const bf16x8*)(P + ((size_t)((g*33 + tc*8 + tt + 1)*96) + i0 + rr)*128 + kc*8);
        qst[r] = *(const bf16x8*)(Q + ((size_t)((g*33 + tc*8 + tt)*96) + j0 + rr)*128 + kc*8);
      }
      __syncthreads();          // previous phase (or csf read) done before overwrite
      #pragma unroll
      for (int r = 0; r < 4; ++r) {
        int c = tid + r * 256;
        int row = c >> 4, kc = c & 15;
        *(bf16x8*)(sb0 + row*XS_LD + kc*8) = pst[r];
        *(bf16x8*)(sb1 + row*XS_LD + kc*8) = qst[r];
      }
      __syncthreads();

      #pragma unroll 2
      for (int tt = 0; tt < 8; ++tt) {
        int prow = tt*8 + ii, qrow = tt*8 + jj;
        bf16x8 a[4];
        #pragma unroll
        for (int ks = 0; ks < 4; ++ks) {
          bf16x8 pv = *(const bf16x8*)(sb0 + prow*XS_LD + ks*32 + lg*8);
          bf16x8 qv = *(const bf16x8*)(sb1 + qrow*XS_LD + ks*32 + lg*8);
          #pragma unroll
          for (int m = 0; m < 8; ++m) {
            float s = (float)pv[m] + (float)qv[m] + csf[ks*8 + m];
            a[ks][m] = (bf16_t)fmaxf(s, 0.f);
          }
        }
        f32x4 acc[4];
        #pragma unroll
        for (int nb = 0; nb < 4; ++nb) {
          f32x4 t4 = {0.f,0.f,0.f,0.f};
          #pragma unroll
          for (int ks = 0; ks < 4; ++ks)
            t4 = __builtin_amdgcn_mfma_f32_16x16x32_bf16(a[ks], wb[nb][ks], t4, 0, 0, 0);
          acc[nb] = t4;
        }
        float partial[4];
        #pragma unroll
        for (int r = 0; r < 4; ++r) {
          float ps = 0.f;
          #pragma unroll
          for (int nb = 0; nb < 4; ++nb)
            ps += fmaxf(acc[nb][r] + b2v[nb], 0.f) * w3v[nb];
          partial[r] = ps;
        }
        #pragma unroll
        for (int r = 0; r < 4; ++r) {
          partial[r] += __shfl_xor(partial[r], 1, 16);
          partial[r] += __shfl_xor(partial[r], 2, 16);
          partial[r] += __shfl_xor(partial[r], 4, 16);
          partial[r] += __shfl_xor(partial[r], 8, 16);
        }
        if (lr < 4) {
          float v = (lr == 0) ? partial[0] : (lr == 1) ? partial[1]
                  : (lr == 2) ? partial[2] : partial[3];
          v = dead ? NEGV : (v + b3);
          out_logits[(size_t)((g*32 + tc*8 + tt)*96 + mi)*96 + mj] = v;
        }
      }
    }
  } else {
    // ===== dist head. unit = (g,t,half): 48 rows, waves 0..2 =====
    int u = b - 576;                  // 0..127
    int g = u >> 6, t = (u >> 1) & 31, half = u & 1;
    int r0 = half * 48;
    if (w < 3) {
      bf16x8 a[8];
      #pragma unroll
      for (int ks = 0; ks < 8; ++ks) {
        int h2 = ks >> 2;
        int kk = (ks & 3)*32 + lg*8;
        a[ks] = *(const bf16x8*)(encB + (size_t)((g*33 + t + h2)*96 + r0 + w*16 + lr)*128 + kk);
      }
      #pragma unroll
      for (int nb = 0; nb < 8; ++nb) {
        f32x4 acc = {0.f,0.f,0.f,0.f};
        #pragma unroll
        for (int ks = 0; ks < 8; ++ks) {
          bf16x8 bfr = gfrag(dpW1 + (size_t)(ks*32 + lg*8)*128 + nb*16 + lr, 128);
          acc = __builtin_amdgcn_mfma_f32_16x16x32_bf16(a[ks], bfr, acc, 0, 0, 0);
        }
        int n = nb*16 + lr; float bv = dpb1[n];
        #pragma unroll
        for (int r = 0; r < 4; ++r)
          sb0[(w*16 + lg*4 + r)*XS_LD + n] = (bf16_t)fmaxf(acc[r] + bv, 0.f);
      }
    }
    __syncthreads();
    if (w < 3) {
      bf16x8 a2[4];
      #pragma unroll
      for (int ks = 0; ks < 4; ++ks)
        a2[ks] = *(const bf16x8*)(sb0 + (w*16 + lr)*XS_LD + ks*32 + lg*8);
      f32x4 acc[4];
      #pragma unroll
      for (int nb = 0; nb < 4; ++nb) {
        f32x4 t4 = {0.f,0.f,0.f,0.f};
        #pragma unroll
        for (int ks = 0; ks < 4; ++ks) {
          bf16x8 bfr = gfrag(dpW2 + (size_t)(ks*32 + lg*8)*64 + nb*16 + lr, 64);
          t4 = __builtin_amdgcn_mfma_f32_16x16x32_bf16(a2[ks], bfr, t4, 0, 0, 0);
        }
        acc[nb] = t4;
      }
      float b2v[4], w3v[4];
      #pragma unroll
      for (int nb = 0; nb < 4; ++nb) { b2v[nb] = dpb2[nb*16 + lr]; w3v[nb] = dpW3[nb*16 + lr]; }
      float partial[4];
      #pragma unroll
      for (int r = 0; r < 4; ++r) {
        float ps = 0.f;
        #pragma unroll
        for (int nb = 0; nb < 4; ++nb)
          ps += fmaxf(acc[nb][r] + b2v[nb], 0.f) * w3v[nb];
        partial[r] = ps;
      }
      #pragma unroll
      for (int r = 0; r < 4; ++r) {
        partial[r] += __shfl_xor(partial[r], 1, 16);
        partial[r] += __shfl_xor(partial[r], 2, 16);
        partial[r] += __shfl_xor(partial[r], 4, 16);
        partial[r] += __shfl_xor(partial[r], 8, 16);
      }
      if (lr < 4) {
        float v = (lr == 0) ? partial[0] : (lr == 1) ? partial[1]
                : (lr == 2) ? partial[2] : partial[3];
        v += dpb3[0];
        int row = r0 + w*16 + lg*4 + lr;
        dist_out[(size_t)(g*32 + t)*96 + row] = v;
      }
    }
  }
}

// ---------------------------------------------------------------------------
extern "C" void kernel_launch(void* const* d_in, const int* in_sizes, int n_in,
                              void* d_out, int out_size, void* d_ws, size_t ws_size,
                              hipStream_t stream) {
  (void)in_sizes; (void)n_in; (void)out_size; (void)ws_size;
  const float* x      = (const float*)d_in[0];
  const float* edge_w = (const float*)d_in[1];
  const float* neW1 = (const float*)d_in[5];
  const float* neb1 = (const float*)d_in[6];
  const float* neW2 = (const float*)d_in[7];
  const float* neb2 = (const float*)d_in[8];
  const float* eeW1 = (const float*)d_in[9];
  const float* eeb1 = (const float*)d_in[10];
  const float* eeW2 = (const float*)d_in[11];
  const float* eeb2 = (const float*)d_in[12];
  const float* udW1 = (const float*)d_in[13];
  const float* udb1 = (const float*)d_in[14];
  const float* udW2 = (const float*)d_in[15];
  const float* udb2 = (const float*)d_in[16];
  const float* udW3 = (const float*)d_in[17];
  const float* udb3 = (const float*)d_in[18];
  const float* dpW1 = (const float*)d_in[19];
  const float* dpb1 = (const float*)d_in[20];
  const float* dpW2 = (const float*)d_in[21];
  const float* dpb2 = (const float*)d_in[22];
  const float* dpW3 = (const float*)d_in[23];
  const float* dpb3 = (const float*)d_in[24];

  char* ws = (char*)d_ws;
  size_t off = 0;
  auto alloc = [&](size_t bytes) -> char* {
    off = (off + 255) & ~(size_t)255;
    char* p = ws + off;
    off += bytes;
    return p;
  };
  bf16_t* encB   = (bf16_t*)alloc((size_t)2*33*96*128 * 2);
  bf16_t* Pbuf   = (bf16_t*)alloc((size_t)2*33*96*128 * 2);
  bf16_t* Qbuf   = (bf16_t*)alloc((size_t)2*33*96*128 * 2);
  bf16_t* E2g    = (bf16_t*)alloc((size_t)2*96*96*32  * 2);

  float* out_logits = (float*)d_out;                 // (2,32,96,96)
  float* dist_out   = (float*)d_out + 2*32*96*96;    // (2,32,96)

  kEnc<<<dim3(684), dim3(256), 0, stream>>>(
      x, neW1, neb1, neW2, neb2, udW1, encB, Pbuf, Qbuf,
      edge_w, eeW1, eeb1, eeW2, eeb2, E2g);

  kB<<<dim3(704), dim3(256), 0, stream>>>(
      Pbuf, Qbuf, E2g, udW1, udW2, udb1, udb2, udW3, udb3, edge_w, out_logits,
      encB, dpW1, dpb1, dpW2, dpb2, dpW3, dpb3, dist_out);
}

// Round 8
// 149.399 us; speedup vs baseline: 2.5644x; 1.0416x over previous
//
#include <hip/hip_runtime.h>

// ---------------------------------------------------------------------------
// InterpNetwork: G=2, T=33, D=96, H=128, PROJ=128.
// feat@ud_W1 = P[t+1,i] + Q[t,j] + C[i,j]  (concat split) =>
// per-edge work = layer2 (128->64) + layer3 (64->1) via MFMA.
// Round 8: 2 launches, producer/consumer split across the launch boundary.
//   kEnc (696 blocks): 0..395 node-enc L1+L2 + fused P/Q (gathered weights);
//        396..683 E2 codes + Cs = E2@W1c+b1 -> global (once per edge);
//        684..695 transpose udW2/dpW1/dpW2 -> bf16 [N][K] for kB.
//   kB (1280 blocks): 0..1151 edge-MLP tiles (1 t-chunk, 1 barrier);
//        1152..1279 dist head. All weights vector-loaded.
// ---------------------------------------------------------------------------

typedef __bf16 bf16_t;
typedef bf16_t bf16x8 __attribute__((ext_vector_type(8)));
typedef float  f32x4  __attribute__((ext_vector_type(4)));

#define XS_LD 136
#define NEGV  -1000000000.0f

// gather one B-fragment (8 k-elems at fixed n) from f32 [K][N] weight
__device__ __forceinline__ bf16x8 gfrag(const float* p, int ld) {
  bf16x8 r;
  #pragma unroll
  for (int m = 0; m < 8; ++m) r[m] = (bf16_t)p[m * ld];
  return r;
}

// ---------------------------------------------------------------------------
// kEnc
// ---------------------------------------------------------------------------
__global__ __launch_bounds__(256) void kEnc(
    const float* __restrict__ x,
    const float* __restrict__ neW1, const float* __restrict__ neb1,
    const float* __restrict__ neW2, const float* __restrict__ neb2,
    const float* __restrict__ udW1, const float* __restrict__ udb1,
    bf16_t* __restrict__ encB, bf16_t* __restrict__ P, bf16_t* __restrict__ Q,
    const float* __restrict__ edge_w,
    const float* __restrict__ eeW1, const float* __restrict__ eeb1,
    const float* __restrict__ eeW2, const float* __restrict__ eeb2,
    bf16_t* __restrict__ Csg,
    const float* __restrict__ udW2, const float* __restrict__ dpW1,
    const float* __restrict__ dpW2,
    bf16_t* __restrict__ udW2T, bf16_t* __restrict__ dpW1T,
    bf16_t* __restrict__ dpW2T) {
  __shared__ char smem[16640];
  int bid = blockIdx.x, tid = threadIdx.x;
  int l = tid & 63, w = tid >> 6, lr = l & 15, lg = l >> 4;

  if (bid < 396) {
    // ===== node-enc unit (g,s,mt): 16 rows; L1+L2 in LDS, fused P/Q =====
    bf16_t* sX = (bf16_t*)smem;                    // 16 x 136
    bf16_t* sH = (bf16_t*)smem + 16 * 136;
    bf16_t* sE = (bf16_t*)smem + 32 * 136;
    int ub = bid / 6, mt = bid % 6, g = ub / 33;
    const float* xsrc = x + (size_t)ub * 128 * 192 + g * 96 + mt * 16;  // [h*192+dl]
    #pragma unroll
    for (int i = 0; i < 2; ++i) {
      int t = tid + i * 256;                 // 0..511
      int h = t >> 2, c4 = (t & 3) * 4;
      f32x4 v = *(const f32x4*)(xsrc + h * 192 + c4);
      #pragma unroll
      for (int r = 0; r < 4; ++r) sX[(c4 + r) * 136 + h] = (bf16_t)v[r];
    }
    __syncthreads();

    // layer1: sX -> sH (B-frags gathered from f32 neW1 [128][128])
    {
      bf16x8 a[4];
      #pragma unroll
      for (int ks = 0; ks < 4; ++ks)
        a[ks] = *(const bf16x8*)(sX + lr * 136 + ks * 32 + lg * 8);
      #pragma unroll
      for (int nn = 0; nn < 2; ++nn) {
        int nb = w * 2 + nn;
        bf16x8 bw[4];
        #pragma unroll
        for (int ks = 0; ks < 4; ++ks)
          bw[ks] = gfrag(neW1 + (size_t)(ks*32 + lg*8)*128 + nb*16 + lr, 128);
        f32x4 acc = {0.f,0.f,0.f,0.f};
        #pragma unroll
        for (int ks = 0; ks < 4; ++ks)
          acc = __builtin_amdgcn_mfma_f32_16x16x32_bf16(a[ks], bw[ks], acc, 0, 0, 0);
        float bv = neb1[nb*16 + lr];
        #pragma unroll
        for (int r = 0; r < 4; ++r)
          sH[(lg*4 + r)*136 + nb*16 + lr] = (bf16_t)fmaxf(acc[r] + bv, 0.f);
      }
    }
    __syncthreads();

    // layer2: sH -> sE + encB
    bf16_t* encOut = encB + ((size_t)ub * 96 + mt * 16) * 128;
    {
      bf16x8 a[4];
      #pragma unroll
      for (int ks = 0; ks < 4; ++ks)
        a[ks] = *(const bf16x8*)(sH + lr * 136 + ks * 32 + lg * 8);
      #pragma unroll
      for (int nn = 0; nn < 2; ++nn) {
        int nb = w * 2 + nn;
        bf16x8 bw[4];
        #pragma unroll
        for (int ks = 0; ks < 4; ++ks)
          bw[ks] = gfrag(neW2 + (size_t)(ks*32 + lg*8)*128 + nb*16 + lr, 128);
        f32x4 acc = {0.f,0.f,0.f,0.f};
        #pragma unroll
        for (int ks = 0; ks < 4; ++ks)
          acc = __builtin_amdgcn_mfma_f32_16x16x32_bf16(a[ks], bw[ks], acc, 0, 0, 0);
        float bv = neb2[nb*16 + lr];
        #pragma unroll
        for (int r = 0; r < 4; ++r) {
          bf16_t v = (bf16_t)fmaxf(acc[r] + bv, 0.f);
          sE[(lg*4 + r)*136 + nb*16 + lr] = v;
          encOut[(lg*4 + r)*128 + nb*16 + lr] = v;
        }
      }
    }
    __syncthreads();

    // P/Q projection from sE; udW1 rows 0..127 -> P, 128..255 -> Q.
    {
      bf16x8 a[4];
      #pragma unroll
      for (int ks = 0; ks < 4; ++ks)
        a[ks] = *(const bf16x8*)(sE + lr * 136 + ks * 32 + lg * 8);
      int koff = (w < 2) ? 0 : 128;
      bf16_t* outp = (w < 2) ? P : Q;
      int noff = (w & 1) * 64;
      #pragma unroll
      for (int nb = 0; nb < 4; ++nb) {
        bf16x8 bw[4];
        #pragma unroll
        for (int ks = 0; ks < 4; ++ks)
          bw[ks] = gfrag(udW1 + (size_t)(koff + ks*32 + lg*8)*128 + noff + nb*16 + lr, 128);
        f32x4 acc = {0.f,0.f,0.f,0.f};
        #pragma unroll
        for (int ks = 0; ks < 4; ++ks)
          acc = __builtin_amdgcn_mfma_f32_16x16x32_bf16(a[ks], bw[ks], acc, 0, 0, 0);
        #pragma unroll
        for (int r = 0; r < 4; ++r)
          outp[((size_t)ub*96 + mt*16 + lg*4 + r)*128 + noff + nb*16 + lr] = (bf16_t)acc[r];
      }
    }
  } else if (bid < 684) {
    // ===== E2 codes + Cs = E2@W1c + b1 (64 edges per block) =====
    bf16_t* sE2 = (bf16_t*)smem;                  // [64][40]
    int u3 = bid - 396;
    int e0b = u3 * 64;
    int e = e0b + w * 16 + lr;
    int g = e / 9216, rem = e - g * 9216, i = rem / 96, j = rem - i * 96;
    float wv = edge_w[(g*96 + i)*192 + g*96 + j];
    bf16x8 ah;
    #pragma unroll
    for (int m = 0; m < 8; ++m) {
      int k = lg * 8 + m;
      ah[m] = (bf16_t)fmaxf(wv * eeW1[k] + eeb1[k], 0.f);
    }
    #pragma unroll
    for (int nb = 0; nb < 2; ++nb) {
      bf16x8 bw = gfrag(eeW2 + (size_t)(lg*8)*32 + nb*16 + lr, 32);
      f32x4 acc = {0.f,0.f,0.f,0.f};
      acc = __builtin_amdgcn_mfma_f32_16x16x32_bf16(ah, bw, acc, 0, 0, 0);
      float b2 = eeb2[nb*16 + lr];
      #pragma unroll
      for (int r = 0; r < 4; ++r)
        sE2[(w*16 + lg*4 + r)*40 + nb*16 + lr] = (bf16_t)fmaxf(acc[r] + b2, 0.f);
    }
    __syncthreads();
    // C tile: K=32 single MFMA step, W1c = udW1 rows 256..287
    bf16x8 ae = *(const bf16x8*)(sE2 + (w*16 + lr)*40 + lg*8);
    #pragma unroll
    for (int nb = 0; nb < 8; ++nb) {
      bf16x8 bw = gfrag(udW1 + (size_t)(256 + lg*8)*128 + nb*16 + lr, 128);
      f32x4 acc = {0.f,0.f,0.f,0.f};
      acc = __builtin_amdgcn_mfma_f32_16x16x32_bf16(ae, bw, acc, 0, 0, 0);
      float b1 = udb1[nb*16 + lr];
      #pragma unroll
      for (int r = 0; r < 4; ++r)
        Csg[((size_t)e0b + w*16 + lg*4 + r)*128 + nb*16 + lr] = (bf16_t)(acc[r] + b1);
    }
  } else {
    // ===== transpose units: f32 [K][N] -> bf16 [N][K] for kB =====
    static const unsigned char tS[12]  = {0,0, 1,1,1,1,1,1,1,1, 2,2};
    static const short tLdS[12] = {64,64, 128,128,128,128,128,128,128,128, 64,64};
    static const short tLdD[12] = {128,128, 256,256,256,256,256,256,256,256, 128,128};
    static const short tR0[12]  = {0,64, 0,0,64,64,128,128,192,192, 0,64};
    static const short tC0[12]  = {0,0, 0,64,0,64,0,64,0,64, 0,0};
    int u = bid - 684;
    const float* S = (tS[u] == 0) ? udW2 : (tS[u] == 1) ? dpW1 : dpW2;
    bf16_t* Dst = (tS[u] == 0) ? udW2T : (tS[u] == 1) ? dpW1T : dpW2T;
    int ldS = tLdS[u], ldD = tLdD[u], r0 = tR0[u], c0 = tC0[u];
    float (*tile)[65] = (float(*)[65])smem;
    #pragma unroll
    for (int i = 0; i < 16; ++i) {
      int idx = tid + i * 256, r = idx >> 6, c = idx & 63;
      tile[r][c] = S[(r0 + r) * ldS + c0 + c];
    }
    __syncthreads();
    #pragma unroll
    for (int i = 0; i < 16; ++i) {
      int idx = tid + i * 256, n = idx >> 6, k = idx & 63;
      Dst[(c0 + n) * ldD + r0 + k] = (bf16_t)tile[k][n];
    }
  }
}

// ---------------------------------------------------------------------------
// kB: blocks 0..1151 = edge MLP tiles (jt,it,z); 1152..1279 = dist head.
// ---------------------------------------------------------------------------
__global__ __launch_bounds__(256) void kB(
    const bf16_t* __restrict__ P, const bf16_t* __restrict__ Q,
    const bf16_t* __restrict__ Csg, const bf16_t* __restrict__ udW2T,
    const float* __restrict__ udb2,
    const float* __restrict__ udW3, const float* __restrict__ udb3,
    const float* __restrict__ edge_w, float* __restrict__ out_logits,
    const bf16_t* __restrict__ encB,
    const bf16_t* __restrict__ dpW1T, const float* __restrict__ dpb1,
    const bf16_t* __restrict__ dpW2T, const float* __restrict__ dpb2,
    const float* __restrict__ dpW3, const float* __restrict__ dpb3,
    float* __restrict__ dist_out) {
  __shared__ bf16_t smem[2 * 64 * XS_LD];          // 34.8 KB
  bf16_t* sb0 = smem;
  bf16_t* sb1 = smem + 64 * XS_LD;
  int b = blockIdx.x, tid = threadIdx.x;
  int l = tid & 63, w = tid >> 6, lr = l & 15, lg = l >> 4;

  if (b < 1152) {
    int jt = b % 12, it = (b / 12) % 12, z = b / 144;
    int g = z >> 2, tc = z & 3;
    int i0 = it * 8, j0 = jt * 8;
    int e_loc = w * 16 + lr, ii = e_loc >> 3, jj = e_loc & 7;

    // issue P/Q slab loads (regs)
    bf16x8 pst[4], qst[4];
    #pragma unroll
    for (int r = 0; r < 4; ++r) {
      int c = tid + r * 256;
      int row = c >> 4, kc = c & 15;
      int tt = row >> 3, rr = row & 7;
      pst[r] = *(const bf16x8*)(P + ((size_t)((g*33 + tc*8 + tt + 1)*96) + i0 + rr)*128 + kc*8);
      qst[r] = *(const bf16x8*)(Q + ((size_t)((g*33 + tc*8 + tt)*96) + j0 + rr)*128 + kc*8);
    }
    // csf straight from global Cs (b1 already folded)
    int eg = g*9216 + (i0 + ii)*96 + j0 + jj;
    float csf[32];
    #pragma unroll
    for (int ks = 0; ks < 4; ++ks) {
      bf16x8 cv = *(const bf16x8*)(Csg + (size_t)eg*128 + ks*32 + lg*8);
      #pragma unroll
      for (int m = 0; m < 8; ++m) csf[ks*8 + m] = (float)cv[m];
    }
    // layer-2/3 weights (vectorized from transposed)
    bf16x8 wb[4][4];
    #pragma unroll
    for (int nb = 0; nb < 4; ++nb)
      #pragma unroll
      for (int ks = 0; ks < 4; ++ks)
        wb[nb][ks] = *(const bf16x8*)(udW2T + (nb*16 + lr)*128 + ks*32 + lg*8);
    float b2v[4], w3v[4];
    #pragma unroll
    for (int nb = 0; nb < 4; ++nb) { b2v[nb] = udb2[nb*16 + lr]; w3v[nb] = udW3[nb*16 + lr]; }
    float b3 = udb3[0];

    // mask (hoisted; valid for lanes lr<4 at store)
    int orow = w*16 + lg*4 + (lr & 3);
    int mi = i0 + (orow >> 3), mj = j0 + (orow & 7);
    float ewv = edge_w[(g*96 + mi)*192 + g*96 + mj];
    bool dead = (ewv == 0.0f) && (mi != mj);

    // write slabs, single barrier
    #pragma unroll
    for (int r = 0; r < 4; ++r) {
      int c = tid + r * 256;
      int row = c >> 4, kc = c & 15;
      *(bf16x8*)(sb0 + row*XS_LD + kc*8) = pst[r];
      *(bf16x8*)(sb1 + row*XS_LD + kc*8) = qst[r];
    }
    __syncthreads();

    // t-loop: no barriers, no global loads
    #pragma unroll 2
    for (int tt = 0; tt < 8; ++tt) {
      int prow = tt*8 + ii, qrow = tt*8 + jj;
      bf16x8 a[4];
      #pragma unroll
      for (int ks = 0; ks < 4; ++ks) {
        bf16x8 pv = *(const bf16x8*)(sb0 + prow*XS_LD + ks*32 + lg*8);
        bf16x8 qv = *(const bf16x8*)(sb1 + qrow*XS_LD + ks*32 + lg*8);
        #pragma unroll
        for (int m = 0; m < 8; ++m) {
          float s = (float)pv[m] + (float)qv[m] + csf[ks*8 + m];
          a[ks][m] = (bf16_t)fmaxf(s, 0.f);
        }
      }
      f32x4 acc[4];
      #pragma unroll
      for (int nb = 0; nb < 4; ++nb) {
        f32x4 t4 = {0.f,0.f,0.f,0.f};
        #pragma unroll
        for (int ks = 0; ks < 4; ++ks)
          t4 = __builtin_amdgcn_mfma_f32_16x16x32_bf16(a[ks], wb[nb][ks], t4, 0, 0, 0);
        acc[nb] = t4;
      }
      float partial[4];
      #pragma unroll
      for (int r = 0; r < 4; ++r) {
        float ps = 0.f;
        #pragma unroll
        for (int nb = 0; nb < 4; ++nb)
          ps += fmaxf(acc[nb][r] + b2v[nb], 0.f) * w3v[nb];
        partial[r] = ps;
      }
      #pragma unroll
      for (int r = 0; r < 4; ++r) {
        partial[r] += __shfl_xor(partial[r], 1, 16);
        partial[r] += __shfl_xor(partial[r], 2, 16);
        partial[r] += __shfl_xor(partial[r], 4, 16);
        partial[r] += __shfl_xor(partial[r], 8, 16);
      }
      if (lr < 4) {
        float v = (lr == 0) ? partial[0] : (lr == 1) ? partial[1]
                : (lr == 2) ? partial[2] : partial[3];
        v = dead ? NEGV : (v + b3);
        out_logits[(size_t)((g*32 + tc*8 + tt)*96 + mi)*96 + mj] = v;
      }
    }
  } else {
    // ===== dist head. unit = (g,t,half): 48 rows, waves 0..2 =====
    int u = b - 1152;
    int g = u >> 6, t = (u >> 1) & 31, half = u & 1;
    int r0 = half * 48;
    if (w < 3) {
      bf16x8 a[8];
      #pragma unroll
      for (int ks = 0; ks < 8; ++ks) {
        int h2 = ks >> 2;
        int kk = (ks & 3)*32 + lg*8;
        a[ks] = *(const bf16x8*)(encB + (size_t)((g*33 + t + h2)*96 + r0 + w*16 + lr)*128 + kk);
      }
      #pragma unroll
      for (int nb = 0; nb < 8; ++nb) {
        f32x4 acc = {0.f,0.f,0.f,0.f};
        #pragma unroll
        for (int ks = 0; ks < 8; ++ks) {
          bf16x8 bfr = *(const bf16x8*)(dpW1T + (size_t)(nb*16 + lr)*256 + ks*32 + lg*8);
          acc = __builtin_amdgcn_mfma_f32_16x16x32_bf16(a[ks], bfr, acc, 0, 0, 0);
        }
        int n = nb*16 + lr; float bv = dpb1[n];
        #pragma unroll
        for (int r = 0; r < 4; ++r)
          sb0[(w*16 + lg*4 + r)*XS_LD + n] = (bf16_t)fmaxf(acc[r] + bv, 0.f);
      }
    }
    __syncthreads();
    if (w < 3) {
      bf16x8 a2[4];
      #pragma unroll
      for (int ks = 0; ks < 4; ++ks)
        a2[ks] = *(const bf16x8*)(sb0 + (w*16 + lr)*XS_LD + ks*32 + lg*8);
      f32x4 acc[4];
      #pragma unroll
      for (int nb = 0; nb < 4; ++nb) {
        f32x4 t4 = {0.f,0.f,0.f,0.f};
        #pragma unroll
        for (int ks = 0; ks < 4; ++ks) {
          bf16x8 bfr = *(const bf16x8*)(dpW2T + (nb*16 + lr)*128 + ks*32 + lg*8);
          t4 = __builtin_amdgcn_mfma_f32_16x16x32_bf16(a2[ks], bfr, t4, 0, 0, 0);
        }
        acc[nb] = t4;
      }
      float b2v[4], w3v[4];
      #pragma unroll
      for (int nb = 0; nb < 4; ++nb) { b2v[nb] = dpb2[nb*16 + lr]; w3v[nb] = dpW3[nb*16 + lr]; }
      float partial[4];
      #pragma unroll
      for (int r = 0; r < 4; ++r) {
        float ps = 0.f;
        #pragma unroll
        for (int nb = 0; nb < 4; ++nb)
          ps += fmaxf(acc[nb][r] + b2v[nb], 0.f) * w3v[nb];
        partial[r] = ps;
      }
      #pragma unroll
      for (int r = 0; r < 4; ++r) {
        partial[r] += __shfl_xor(partial[r], 1, 16);
        partial[r] += __shfl_xor(partial[r], 2, 16);
        partial[r] += __shfl_xor(partial[r], 4, 16);
        partial[r] += __shfl_xor(partial[r], 8, 16);
      }
      if (lr < 4) {
        float v = (lr == 0) ? partial[0] : (lr == 1) ? partial[1]
                : (lr == 2) ? partial[2] : partial[3];
        v += dpb3[0];
        int row = r0 + w*16 + lg*4 + lr;
        dist_out[(size_t)(g*32 + t)*96 + row] = v;
      }
    }
  }
}

// ---------------------------------------------------------------------------
extern "C" void kernel_launch(void* const* d_in, const int* in_sizes, int n_in,
                              void* d_out, int out_size, void* d_ws, size_t ws_size,
                              hipStream_t stream) {
  (void)in_sizes; (void)n_in; (void)out_size; (void)ws_size;
  const float* x      = (const float*)d_in[0];
  const float* edge_w = (const float*)d_in[1];
  const float* neW1 = (const float*)d_in[5];
  const float* neb1 = (const float*)d_in[6];
  const float* neW2 = (const float*)d_in[7];
  const float* neb2 = (const float*)d_in[8];
  const float* eeW1 = (const float*)d_in[9];
  const float* eeb1 = (const float*)d_in[10];
  const float* eeW2 = (const float*)d_in[11];
  const float* eeb2 = (const float*)d_in[12];
  const float* udW1 = (const float*)d_in[13];
  const float* udb1 = (const float*)d_in[14];
  const float* udW2 = (const float*)d_in[15];
  const float* udb2 = (const float*)d_in[16];
  const float* udW3 = (const float*)d_in[17];
  const float* udb3 = (const float*)d_in[18];
  const float* dpW1 = (const float*)d_in[19];
  const float* dpb1 = (const float*)d_in[20];
  const float* dpW2 = (const float*)d_in[21];
  const float* dpb2 = (const float*)d_in[22];
  const float* dpW3 = (const float*)d_in[23];
  const float* dpb3 = (const float*)d_in[24];

  char* ws = (char*)d_ws;
  size_t off = 0;
  auto alloc = [&](size_t bytes) -> char* {
    off = (off + 255) & ~(size_t)255;
    char* p = ws + off;
    off += bytes;
    return p;
  };
  bf16_t* encB   = (bf16_t*)alloc((size_t)2*33*96*128 * 2);
  bf16_t* Pbuf   = (bf16_t*)alloc((size_t)2*33*96*128 * 2);
  bf16_t* Qbuf   = (bf16_t*)alloc((size_t)2*33*96*128 * 2);
  bf16_t* Csg    = (bf16_t*)alloc((size_t)2*96*96*128 * 2);   // 4.7 MB
  bf16_t* udW2T  = (bf16_t*)alloc(8192  * 2);
  bf16_t* dpW1T  = (bf16_t*)alloc(32768 * 2);
  bf16_t* dpW2T  = (bf16_t*)alloc(8192  * 2);

  float* out_logits = (float*)d_out;                 // (2,32,96,96)
  float* dist_out   = (float*)d_out + 2*32*96*96;    // (2,32,96)

  kEnc<<<dim3(696), dim3(256), 0, stream>>>(
      x, neW1, neb1, neW2, neb2, udW1, udb1, encB, Pbuf, Qbuf,
      edge_w, eeW1, eeb1, eeW2, eeb2, Csg,
      udW2, dpW1, dpW2, udW2T, dpW1T, dpW2T);

  kB<<<dim3(1280), dim3(256), 0, stream>>>(
      Pbuf, Qbuf, Csg, udW2T, udb2, udW3, udb3, edge_w, out_logits,
      encB, dpW1T, dpb1, dpW2T, dpb2, dpW3, dpb3, dist_out);
}